// Round 8
// baseline (243.942 us; speedup 1.0000x reference)
//
#include <hip/hip_runtime.h>
#include <hip/hip_bf16.h>

typedef short short8 __attribute__((ext_vector_type(8)));
typedef float f32x4 __attribute__((ext_vector_type(4)));
typedef float f32x16 __attribute__((ext_vector_type(16)));

#define MFMA16(a, b, c) __builtin_amdgcn_mfma_f32_16x16x32_bf16((a), (b), (c), 0, 0, 0)
#define MFMA32(a, b, c) __builtin_amdgcn_mfma_f32_32x32x16_bf16((a), (b), (c), 0, 0, 0)

// async global->LDS, 16B per lane; LDS dest = wave-uniform base + lane*16
#define GLOAD16(gp, lp)                                                    \
    __builtin_amdgcn_global_load_lds(                                      \
        (const __attribute__((address_space(1))) unsigned int*)(gp),       \
        (__attribute__((address_space(3))) unsigned int*)(lp), 16, 0, 0)

__device__ __forceinline__ unsigned short f2b(float x) {
    unsigned int u = __float_as_uint(x);
    unsigned int r = u + 0x7FFFu + ((u >> 16) & 1u);
    return (unsigned short)(r >> 16);
}

#if __has_builtin(__builtin_amdgcn_cvt_pk_bf16_f32)
__device__ __forceinline__ unsigned pack2(float a, float b) {
    auto v = __builtin_amdgcn_cvt_pk_bf16_f32(a, b);
    unsigned u;
    __builtin_memcpy(&u, &v, 4);
    return u;
}
#else
__device__ __forceinline__ unsigned pack2(float a, float b) {
    return (unsigned)f2b(a) | ((unsigned)f2b(b) << 16);
}
#endif

// ---------------------------------------------------------------- fused preprocessing
// blocks [0,8192): x -> bf16 cast. [8192,8960): w_qkv transpose. [8960,9216): w_out.
__device__ __forceinline__ void transpose_body(const float* __restrict__ in,
                                               unsigned short* __restrict__ out,
                                               int K, int N, int k0, int n0,
                                               unsigned short* Ls, int tid) {
    const int krow = tid >> 4, nc4 = (tid & 15) * 4;
#pragma unroll
    for (int p = 0; p < 4; p++) {
        float4 v = *(const float4*)(in + (size_t)(k0 + krow + p * 16) * N + n0 + nc4);
        unsigned* d32 = (unsigned*)(Ls + (krow + p * 16) * 66 + nc4);
        d32[0] = pack2(v.x, v.y);
        d32[1] = pack2(v.z, v.w);
    }
    __syncthreads();
    const int n = tid >> 3, kc = (tid & 7) * 8;
#pragma unroll
    for (int p = 0; p < 2; p++) {
        int nn = n + p * 32;
        unsigned short w[8];
#pragma unroll
        for (int j = 0; j < 8; j++) w[j] = Ls[(kc + j) * 66 + nn];
        *(short8*)(out + (size_t)(n0 + nn) * K + k0 + kc) = *(short8*)w;
    }
}

__global__ __launch_bounds__(256) void prep_kernel(const float* __restrict__ x,
                                                   unsigned short* __restrict__ xb,
                                                   const float* __restrict__ w_qkv,
                                                   unsigned short* __restrict__ wqkvT,
                                                   const float* __restrict__ w_out,
                                                   unsigned short* __restrict__ woutT) {
    __shared__ unsigned short Ls[64 * 66];
    const int bid = blockIdx.x, tid = threadIdx.x;
    if (bid < 8192) {
        int i = bid * 256 + tid;   // n4 = 8192*256 exactly
        float4 v = ((const float4*)x)[i];
        ushort4 o;
        o.x = f2b(v.x); o.y = f2b(v.y); o.z = f2b(v.z); o.w = f2b(v.w);
        ((ushort4*)xb)[i] = o;
    } else if (bid < 8960) {
        const int b2 = bid - 8192;          // 768 blocks: N=3072 (48) x K=1024 (16)
        transpose_body(w_qkv, wqkvT, 1024, 3072, (b2 / 48) * 64, (b2 % 48) * 64, Ls, tid);
    } else {
        const int b3 = bid - 8960;          // 256 blocks: 16 x 16
        transpose_body(w_out, woutT, 1024, 1024, (b3 >> 4) * 64, (b3 & 15) * 64, Ls, tid);
    }
}

// ---------------------------------------------------------------- fused QKV GEMM
// blocks [0,256): Q/K path — 256x256 tile, BK=64, 128KB LDS, 4-phase vmcnt(6),
//   swapped MFMA (D^T) -> packed 8B stores. 1 block/CU, exactly 1 round.
// blocks [256,512): V path — 128x256 tile, 96KB LDS, 4-phase vmcnt(5),
//   sigma-permuted LDS-bounce transpose to Vt[bh][64 d][2048 t].
__global__ __launch_bounds__(512, 2) void gemm_qkv(const unsigned short* __restrict__ A,
                                                   const unsigned short* __restrict__ BtQK,
                                                   const unsigned short* __restrict__ BtV,
                                                   unsigned short* __restrict__ Qb,
                                                   unsigned short* __restrict__ Kb,
                                                   unsigned short* __restrict__ Vt) {
    __shared__ __align__(16) unsigned short smem[65536]; // 128KB, V path uses first 96KB

    const int tid  = threadIdx.x;
    const int wave = tid >> 6;
    const int lane = tid & 63;
    const int l32  = lane & 31;
    const int hi   = lane >> 5;
    const int wr   = wave >> 2;
    const int wc   = wave & 3;
    const int sw7  = l32 & 7;
    const int srow = tid >> 3;
    const int cswz = (((tid & 7) ^ ((tid >> 3) & 7)) * 8);

    if (blockIdx.x < 256) {
        // ---------------- Q/K path ----------------
        const int bid = blockIdx.x;
        const int sid = (bid & 7) * 32 + (bid >> 3);
        const int bx  = sid & 7;
        const int by  = sid >> 3;
        const int m0 = by * 256;
        const int n0 = bx * 256;

        const unsigned short* gA = A    + (size_t)(m0 + srow) * 1024 + cswz;
        const unsigned short* gB = BtQK + (size_t)(n0 + srow) * 1024 + cswz;

#define STAGE_A(buf, h, kt) do {                                              \
        const unsigned short* _g = gA + (size_t)((h) * 128) * 1024 + (kt) * 64; \
        unsigned short* _l = smem + (buf) * 16384 + (h) * 8192 + wave * 512;  \
        GLOAD16(_g, _l);                                                      \
        GLOAD16(_g + 65536, _l + 4096);                                       \
    } while (0)
#define STAGE_B(buf, h, kt) do {                                              \
        const unsigned short* _g = gB + (size_t)((h) * 128) * 1024 + (kt) * 64; \
        unsigned short* _l = smem + 32768 + (buf) * 16384 + (h) * 8192 + wave * 512; \
        GLOAD16(_g, _l);                                                      \
        GLOAD16(_g + 65536, _l + 4096);                                       \
    } while (0)

        const int aoff = (wr * 128 + l32) * 64;
        const int boff = (wc * 64 + l32) * 64;

        f32x16 acc[4][2] = {};

        STAGE_A(0, 0, 0); STAGE_A(0, 1, 0); STAGE_B(0, 0, 0); STAGE_B(0, 1, 0);
        STAGE_B(1, 0, 1); STAGE_B(1, 1, 1); STAGE_A(1, 0, 1);
        asm volatile("s_waitcnt vmcnt(6)" ::: "memory");
        __builtin_amdgcn_s_barrier();

#pragma unroll
        for (int t = 0; t < 16; ++t) {
            const int b = t & 1;
            const unsigned short* Ab = smem + b * 16384;
            const unsigned short* Bb = smem + 32768 + b * 16384;

            short8 afLo[2][4], afHi[2][4], bf0[4], bf1[4];

            // phase 1: afLo + bf0 | stage A1(t+1) | q0
#pragma unroll
            for (int rf = 0; rf < 2; ++rf)
#pragma unroll
                for (int ks = 0; ks < 4; ++ks)
                    afLo[rf][ks] = *(const short8*)(Ab + aoff + rf * 2048 + (((ks * 2 + hi) ^ sw7) * 8));
#pragma unroll
            for (int ks = 0; ks < 4; ++ks)
                bf0[ks] = *(const short8*)(Bb + boff + (((ks * 2 + hi) ^ sw7) * 8));
            if (t + 1 < 16) STAGE_A(b ^ 1, 1, t + 1);
            __builtin_amdgcn_s_barrier();
            asm volatile("s_waitcnt lgkmcnt(0)" ::: "memory");
            __builtin_amdgcn_s_setprio(1);
#pragma unroll
            for (int ks = 0; ks < 4; ++ks) {
                acc[0][0] = MFMA32(bf0[ks], afLo[0][ks], acc[0][0]);
                acc[1][0] = MFMA32(bf0[ks], afLo[1][ks], acc[1][0]);
            }
            __builtin_amdgcn_s_setprio(0);
            __builtin_amdgcn_s_barrier();

            // phase 2: bf1 | q1
#pragma unroll
            for (int ks = 0; ks < 4; ++ks)
                bf1[ks] = *(const short8*)(Bb + boff + 2048 + (((ks * 2 + hi) ^ sw7) * 8));
            __builtin_amdgcn_s_barrier();
            asm volatile("s_waitcnt lgkmcnt(0)" ::: "memory");
            __builtin_amdgcn_s_setprio(1);
#pragma unroll
            for (int ks = 0; ks < 4; ++ks) {
                acc[0][1] = MFMA32(bf1[ks], afLo[0][ks], acc[0][1]);
                acc[1][1] = MFMA32(bf1[ks], afLo[1][ks], acc[1][1]);
            }
            __builtin_amdgcn_s_setprio(0);
            __builtin_amdgcn_s_barrier();

            // phase 3: afHi | stage B0,B1(t+2) | q2
#pragma unroll
            for (int rf = 0; rf < 2; ++rf)
#pragma unroll
                for (int ks = 0; ks < 4; ++ks)
                    afHi[rf][ks] = *(const short8*)(Ab + aoff + (2 + rf) * 2048 + (((ks * 2 + hi) ^ sw7) * 8));
            if (t + 2 < 16) { STAGE_B(b, 0, t + 2); STAGE_B(b, 1, t + 2); }
            __builtin_amdgcn_s_barrier();
            asm volatile("s_waitcnt lgkmcnt(0)" ::: "memory");
            __builtin_amdgcn_s_setprio(1);
#pragma unroll
            for (int ks = 0; ks < 4; ++ks) {
                acc[2][0] = MFMA32(bf0[ks], afHi[0][ks], acc[2][0]);
                acc[3][0] = MFMA32(bf0[ks], afHi[1][ks], acc[3][0]);
            }
            __builtin_amdgcn_s_setprio(0);
            __builtin_amdgcn_s_barrier();

            // phase 4: stage A0(t+2) | counted vmcnt | q3
            if (t + 2 < 16) {
                STAGE_A(b, 0, t + 2);
                asm volatile("s_waitcnt vmcnt(6)" ::: "memory");
            } else {
                asm volatile("s_waitcnt vmcnt(0)" ::: "memory");
            }
            __builtin_amdgcn_s_barrier();
            __builtin_amdgcn_s_setprio(1);
#pragma unroll
            for (int ks = 0; ks < 4; ++ks) {
                acc[2][1] = MFMA32(bf1[ks], afHi[0][ks], acc[2][1]);
                acc[3][1] = MFMA32(bf1[ks], afHi[1][ks], acc[3][1]);
            }
            __builtin_amdgcn_s_setprio(0);
            __builtin_amdgcn_s_barrier();
        }
#undef STAGE_A
#undef STAGE_B

        // D^T layout: m-row = frag-row(l32), n-col = (r&3)+8*(r>>2)+4*hi
        unsigned short* outp = (n0 < 1024) ? Qb : Kb;
        const int cb = (n0 < 1024) ? n0 : n0 - 1024;
        const float QS = (n0 < 1024) ? 0.125f * 1.44269504f : 1.0f;
#pragma unroll
        for (int rf = 0; rf < 4; ++rf) {
            const int row = m0 + wr * 128 + rf * 32 + l32;
#pragma unroll
            for (int cf = 0; cf < 2; ++cf)
#pragma unroll
                for (int g = 0; g < 4; ++g) {
                    const int col = cb + wc * 64 + cf * 32 + g * 8 + 4 * hi;
                    uint2 v;
                    v.x = pack2(acc[rf][cf][4 * g + 0] * QS, acc[rf][cf][4 * g + 1] * QS);
                    v.y = pack2(acc[rf][cf][4 * g + 2] * QS, acc[rf][cf][4 * g + 3] * QS);
                    *(uint2*)(outp + (size_t)row * 1024 + col) = v;
                }
        }
    } else {
        // ---------------- V path ----------------
        const int bid = blockIdx.x - 256;
        const int sid = (bid & 7) * 32 + (bid >> 3);
        const int bx  = sid & 3;
        const int by  = sid >> 2;
        const int m0 = by * 128;
        const int n0 = bx * 256;

        const unsigned short* gA = A   + (size_t)(m0 + srow) * 1024 + cswz;
        const unsigned short* gB = BtV + (size_t)(n0 + srow) * 1024 + cswz;

#define STAGE_A(buf, h, kt) do {                                              \
        const unsigned short* _g = gA + (size_t)((h) * 64) * 1024 + (kt) * 64; \
        unsigned short* _l = smem + (buf) * 8192 + (h) * 4096 + wave * 512;   \
        GLOAD16(_g, _l);                                                      \
    } while (0)
#define STAGE_B(buf, h, kt) do {                                              \
        const unsigned short* _g = gB + (size_t)((h) * 128) * 1024 + (kt) * 64; \
        unsigned short* _l = smem + 16384 + (buf) * 16384 + (h) * 8192 + wave * 512; \
        GLOAD16(_g, _l);                                                      \
        GLOAD16(_g + 65536, _l + 4096);                                       \
    } while (0)

        const int aoff = (wr * 64 + l32) * 64;
        const int boff = (wc * 64 + l32) * 64;

        f32x16 acc[2][2] = {};

        STAGE_A(0, 0, 0); STAGE_A(0, 1, 0); STAGE_B(0, 0, 0); STAGE_B(0, 1, 0);
        STAGE_B(1, 0, 1); STAGE_B(1, 1, 1); STAGE_A(1, 0, 1);
        asm volatile("s_waitcnt vmcnt(5)" ::: "memory");
        __builtin_amdgcn_s_barrier();

#pragma unroll
        for (int t = 0; t < 16; ++t) {
            const int b = t & 1;
            const unsigned short* Ab = smem + b * 8192;
            const unsigned short* Bb = smem + 16384 + b * 16384;

            short8 af0[4], af1[4], bf0[4], bf1[4];

            // phase 1: af0 + bf0 | stage A1(t+1) | q0
#pragma unroll
            for (int ks = 0; ks < 4; ++ks)
                af0[ks] = *(const short8*)(Ab + aoff + (((ks * 2 + hi) ^ sw7) * 8));
#pragma unroll
            for (int ks = 0; ks < 4; ++ks)
                bf0[ks] = *(const short8*)(Bb + boff + (((ks * 2 + hi) ^ sw7) * 8));
            if (t + 1 < 16) STAGE_A(b ^ 1, 1, t + 1);
            __builtin_amdgcn_s_barrier();
            asm volatile("s_waitcnt lgkmcnt(0)" ::: "memory");
            __builtin_amdgcn_s_setprio(1);
#pragma unroll
            for (int ks = 0; ks < 4; ++ks)
                acc[0][0] = MFMA32(af0[ks], bf0[ks], acc[0][0]);
            __builtin_amdgcn_s_setprio(0);
            __builtin_amdgcn_s_barrier();

            // phase 2: bf1 | q1
#pragma unroll
            for (int ks = 0; ks < 4; ++ks)
                bf1[ks] = *(const short8*)(Bb + boff + 2048 + (((ks * 2 + hi) ^ sw7) * 8));
            __builtin_amdgcn_s_barrier();
            asm volatile("s_waitcnt lgkmcnt(0)" ::: "memory");
            __builtin_amdgcn_s_setprio(1);
#pragma unroll
            for (int ks = 0; ks < 4; ++ks)
                acc[0][1] = MFMA32(af0[ks], bf1[ks], acc[0][1]);
            __builtin_amdgcn_s_setprio(0);
            __builtin_amdgcn_s_barrier();

            // phase 3: af1 | stage B0,B1(t+2) | q2
#pragma unroll
            for (int ks = 0; ks < 4; ++ks)
                af1[ks] = *(const short8*)(Ab + aoff + 2048 + (((ks * 2 + hi) ^ sw7) * 8));
            if (t + 2 < 16) { STAGE_B(b, 0, t + 2); STAGE_B(b, 1, t + 2); }
            __builtin_amdgcn_s_barrier();
            asm volatile("s_waitcnt lgkmcnt(0)" ::: "memory");
            __builtin_amdgcn_s_setprio(1);
#pragma unroll
            for (int ks = 0; ks < 4; ++ks)
                acc[1][0] = MFMA32(af1[ks], bf0[ks], acc[1][0]);
            __builtin_amdgcn_s_setprio(0);
            __builtin_amdgcn_s_barrier();

            // phase 4: stage A0(t+2) | counted vmcnt | q3
            if (t + 2 < 16) {
                STAGE_A(b, 0, t + 2);
                asm volatile("s_waitcnt vmcnt(5)" ::: "memory");
            } else {
                asm volatile("s_waitcnt vmcnt(0)" ::: "memory");
            }
            __builtin_amdgcn_s_barrier();
            __builtin_amdgcn_s_setprio(1);
#pragma unroll
            for (int ks = 0; ks < 4; ++ks)
                acc[1][1] = MFMA32(af1[ks], bf1[ks], acc[1][1]);
            __builtin_amdgcn_s_setprio(0);
            __builtin_amdgcn_s_barrier();
        }
#undef STAGE_A
#undef STAGE_B

        // bounce: [t][d] -> Vt[bh][d][t] with sigma order (sigma(8Q+e)=4Q+(e&3)+16*(e>=4))
        const int bb = m0 >> 11, t0b = m0 & 2047;
        const int hbase = n0 >> 6;
        unsigned short* reg = smem + wc * 8192;
#pragma unroll
        for (int rf = 0; rf < 2; ++rf)
#pragma unroll
            for (int cf = 0; cf < 2; ++cf)
#pragma unroll
                for (int rg = 0; rg < 4; ++rg) {
                    const int tl = wr * 64 + rf * 32 + rg * 8 + 4 * hi;
                    const int d  = cf * 32 + l32;
                    const int w  = d * 64 + ((tl >> 1) ^ (4 * (d & 7)));
                    uint2 v;
                    v.x = pack2(acc[rf][cf][4 * rg + 0], acc[rf][cf][4 * rg + 1]);
                    v.y = pack2(acc[rf][cf][4 * rg + 2], acc[rf][cf][4 * rg + 3]);
                    *(uint2*)(reg + 2 * w) = v;
                }
        __syncthreads();
#pragma unroll
        for (int it = 0; it < 8; ++it) {
            const int id = it * 512 + tid;
            const int hh = id >> 10, d = (id >> 4) & 63, k = id & 15;
            const int kb = k >> 2, kl = k & 3;
            const int xx = 4 * (d & 7);
            const unsigned short* bp = smem + hh * 8192 + 2 * (d * 64);
            uint2 lo  = *(const uint2*)(bp + 2 * ((16 * kb + 2 * kl) ^ xx));
            uint2 hi2 = *(const uint2*)(bp + 2 * ((16 * kb + 2 * kl + 8) ^ xx));
            uint2 parts[2] = {lo, hi2};
            short8 v; __builtin_memcpy(&v, parts, 16);
            *(short8*)(Vt + ((size_t)((bb * 16 + hbase + hh) * 64 + d)) * 2048 + t0b + k * 8) = v;
        }
    }
}

// ---------------------------------------------------------------- out-proj GEMM
// 128x256 tile, BK=64, 8 waves (2Mx4N), double-buffered 96KB LDS, 4-phase
// counted-vmcnt(5) schedule (per-wave 64x64, acc[2][2]).
__global__ __launch_bounds__(512, 2) void gemm_out(const unsigned short* __restrict__ A,
                                                   const unsigned short* __restrict__ Bt,
                                                   float* __restrict__ C) {
    __shared__ __align__(16) unsigned short smem[49152]; // A[2][8192] | B[2][16384]

    const int tid  = threadIdx.x;
    const int wave = tid >> 6;
    const int lane = tid & 63;
    const int l32  = lane & 31;
    const int hi   = lane >> 5;
    const int wr   = wave >> 2;   // 0..1 (M)
    const int wc   = wave & 3;    // 0..3 (N)

    const int bid = blockIdx.x;
    const int sid = (bid & 7) * 32 + (bid >> 3);
    const int bx  = sid & 3;      // 4 N-blocks
    const int by  = sid >> 2;     // 64 M-blocks
    const int m0 = by * 128;
    const int n0 = bx * 256;

    const int srow = tid >> 3;
    const int cswz = (((tid & 7) ^ ((tid >> 3) & 7)) * 8);
    const unsigned short* gA = A  + (size_t)(m0 + srow) * 1024 + cswz;
    const unsigned short* gB = Bt + (size_t)(n0 + srow) * 1024 + cswz;

#define STAGE_A(buf, h, kt) do {                                              \
        const unsigned short* _g = gA + (size_t)((h) * 64) * 1024 + (kt) * 64; \
        unsigned short* _l = smem + (buf) * 8192 + (h) * 4096 + wave * 512;   \
        GLOAD16(_g, _l);                                                      \
    } while (0)
#define STAGE_B(buf, h, kt) do {                                              \
        const unsigned short* _g = gB + (size_t)((h) * 128) * 1024 + (kt) * 64; \
        unsigned short* _l = smem + 16384 + (buf) * 16384 + (h) * 8192 + wave * 512; \
        GLOAD16(_g, _l);                                                      \
        GLOAD16(_g + 65536, _l + 4096);                                       \
    } while (0)

    const int sw7  = l32 & 7;
    const int aoff = (wr * 64 + l32) * 64;
    const int boff = (wc * 64 + l32) * 64;

    f32x16 acc[2][2] = {};

    STAGE_A(0, 0, 0); STAGE_A(0, 1, 0); STAGE_B(0, 0, 0); STAGE_B(0, 1, 0);
    STAGE_B(1, 0, 1); STAGE_B(1, 1, 1); STAGE_A(1, 0, 1);
    asm volatile("s_waitcnt vmcnt(5)" ::: "memory");
    __builtin_amdgcn_s_barrier();

#pragma unroll
    for (int t = 0; t < 16; ++t) {
        const int b = t & 1;
        const unsigned short* Ab = smem + b * 8192;
        const unsigned short* Bb = smem + 16384 + b * 16384;

        short8 af0[4], af1[4], bf0[4], bf1[4];

        // phase 1: af0 + bf0 | stage A1(t+1) | q0
#pragma unroll
        for (int ks = 0; ks < 4; ++ks)
            af0[ks] = *(const short8*)(Ab + aoff + (((ks * 2 + hi) ^ sw7) * 8));
#pragma unroll
        for (int ks = 0; ks < 4; ++ks)
            bf0[ks] = *(const short8*)(Bb + boff + (((ks * 2 + hi) ^ sw7) * 8));
        if (t + 1 < 16) STAGE_A(b ^ 1, 1, t + 1);
        __builtin_amdgcn_s_barrier();
        asm volatile("s_waitcnt lgkmcnt(0)" ::: "memory");
        __builtin_amdgcn_s_setprio(1);
#pragma unroll
        for (int ks = 0; ks < 4; ++ks)
            acc[0][0] = MFMA32(af0[ks], bf0[ks], acc[0][0]);
        __builtin_amdgcn_s_setprio(0);
        __builtin_amdgcn_s_barrier();

        // phase 2: bf1 | q1
#pragma unroll
        for (int ks = 0; ks < 4; ++ks)
            bf1[ks] = *(const short8*)(Bb + boff + 2048 + (((ks * 2 + hi) ^ sw7) * 8));
        __builtin_amdgcn_s_barrier();
        asm volatile("s_waitcnt lgkmcnt(0)" ::: "memory");
        __builtin_amdgcn_s_setprio(1);
#pragma unroll
        for (int ks = 0; ks < 4; ++ks)
            acc[0][1] = MFMA32(af0[ks], bf1[ks], acc[0][1]);
        __builtin_amdgcn_s_setprio(0);
        __builtin_amdgcn_s_barrier();

        // phase 3: af1 | stage B0,B1(t+2) | q2
#pragma unroll
        for (int ks = 0; ks < 4; ++ks)
            af1[ks] = *(const short8*)(Ab + aoff + 2048 + (((ks * 2 + hi) ^ sw7) * 8));
        if (t + 2 < 16) { STAGE_B(b, 0, t + 2); STAGE_B(b, 1, t + 2); }
        __builtin_amdgcn_s_barrier();
        asm volatile("s_waitcnt lgkmcnt(0)" ::: "memory");
        __builtin_amdgcn_s_setprio(1);
#pragma unroll
        for (int ks = 0; ks < 4; ++ks)
            acc[1][0] = MFMA32(af1[ks], bf0[ks], acc[1][0]);
        __builtin_amdgcn_s_setprio(0);
        __builtin_amdgcn_s_barrier();

        // phase 4: stage A0(t+2) | counted vmcnt | q3
        if (t + 2 < 16) {
            STAGE_A(b, 0, t + 2);
            asm volatile("s_waitcnt vmcnt(5)" ::: "memory");
        } else {
            asm volatile("s_waitcnt vmcnt(0)" ::: "memory");
        }
        __builtin_amdgcn_s_barrier();
        __builtin_amdgcn_s_setprio(1);
#pragma unroll
        for (int ks = 0; ks < 4; ++ks)
            acc[1][1] = MFMA32(af1[ks], bf1[ks], acc[1][1]);
        __builtin_amdgcn_s_setprio(0);
        __builtin_amdgcn_s_barrier();
    }
#undef STAGE_A
#undef STAGE_B

#pragma unroll
    for (int rf = 0; rf < 2; ++rf)
#pragma unroll
        for (int cf = 0; cf < 2; ++cf)
#pragma unroll
            for (int r = 0; r < 16; ++r) {
                int row = m0 + wr * 64 + rf * 32 + (r & 3) + 8 * (r >> 2) + 4 * hi;
                int col = n0 + wc * 64 + cf * 32 + l32;
                C[(size_t)row * 1024 + col] = acc[rf][cf][r];
            }
}

// ---------------------------------------------------------------- flash attention (S^T formulation)
// 512 uniform paired blocks x 512 threads; pass0 = q-block 15-p, pass1 = q-block p
// (exactly 34 x 64-t tile iterations per block). 3-slot LDS ring of 64-t tiles
// (48KB -> 3 blocks/CU, 24 waves/CU, all 512 blocks co-resident), ONE barrier per
// tile + counted vmcnt(2) prefetch (distance 1). Ring safety: fast wave stages
// slot (j+2)%3 while slowest computes slot j%3 — always distinct; pass-end
// barrier protects ring reuse. In-register sigma-P, MFMA-ones row-sum. Q pre-scaled.
__global__ __launch_bounds__(512, 6) void attention_kernel(const unsigned short* Qb,
                                                           const unsigned short* Kb,
                                                           const unsigned short* Vt,
                                                           unsigned short* attn) {
    const int T = 2048;
    const int bi = blockIdx.x;
    const int pp = bi >> 6;          // 0..7 pair index
    const int hb = bi & 63;
    const int b = hb >> 4, h = hb & 15;
    const int tid = threadIdx.x, wave = tid >> 6, lane = tid & 63;
    const int l16 = lane & 15, quad = lane >> 4;

    const unsigned short* Qp  = Qb + (size_t)b * T * 1024 + h * 64;
    const unsigned short* Kp  = Kb + (size_t)b * T * 1024 + h * 64;
    const unsigned short* Vbh = Vt + ((size_t)(b * 16 + h) * 64) * 2048;

    // ring slot (8192 shorts): K[2][64t][32d] (4096) | V[2][64d][32t] (4096)
    __shared__ __align__(16) unsigned short smem[3][8192];

    const f32x4 fz = {};
    short8 onesf;
#pragma unroll
    for (int e = 0; e < 8; e++) onesf[e] = (short)0x3F80;

    const int srow = lane >> 2;
    const int scol = (((lane & 3) ^ ((lane >> 3) & 3)) * 8);
    const int sw8  = ((l16 >> 1) & 3) * 8;

    // staging assignment: waves 0-3 -> K (panel=d-half, chunk-pair), 4-7 -> V
    const unsigned short* gs;
    size_t ktstep, jstep;
    int lofs;
    if (wave < 4) {
        const int p = wave >> 1, cp = wave & 1;
        gs = Kp + (size_t)(cp * 32 + srow) * 1024 + p * 32 + scol;
        ktstep = (size_t)64 * 1024; jstep = (size_t)16 * 1024;
        lofs = p * 2048 + cp * 1024;
    } else {
        const int u = wave - 4, th = u >> 1, cp = u & 1;
        gs = Vbh + (size_t)(cp * 32 + srow) * 2048 + th * 32 + scol;
        ktstep = (size_t)64; jstep = (size_t)16 * 2048;
        lofs = 4096 + th * 2048 + cp * 1024;
    }

// k64 = global 64-t tile index; slot = ring slot
#define STAGE(slot, k64) do {                                  \
        const unsigned short* _g = gs + (size_t)(k64) * ktstep; \
        unsigned short* _l = &smem[slot][0] + lofs;             \
        GLOAD16(_g, _l);                                        \
        GLOAD16(_g + jstep, _l + 512);                          \
    } while (0)

    for (int pass = 0; pass < 2; ++pass) {
        const int qb = pass ? pp : (15 - pp);   // long pass first
        const int qw0 = qb * 128 + wave * 16;

        short8 qf[2];
#pragma unroll
        for (int kd = 0; kd < 2; kd++)
            qf[kd] = *(const short8*)(Qp + (size_t)(qw0 + l16) * 1024 + kd * 32 + quad * 8);
        asm volatile("" ::: "memory");

        f32x4 o[4] = {};
        f32x4 o_l = {};

        const int nt = 2 * qb + 2;              // 64-t tiles 0..nt-1
        STAGE(0, 0);
        int slot = 0;
        for (int j = 0; j < nt; ++j) {
            const int nslot = (slot == 2) ? 0 : slot + 1;
            if (j + 1 < nt) {
                STAGE(nslot, j + 1);
                asm volatile("s_waitcnt vmcnt(2)" ::: "memory");
            } else {
                asm volatile("s_waitcnt vmcnt(0)" ::: "memory");
            }
            __builtin_amdgcn_s_barrier();
            asm volatile("" ::: "memory");

            const int tk0 = j * 64;
            const unsigned short* Kb0 = &smem[slot][0];
            const unsigned short* Kb1 = Kb0 + 2048;
            const unsigned short* Vb0 = Kb0 + 4096;

#pragma unroll
            for (int th = 0; th < 2; th++) {
                const int t0a = tk0 + th * 32;
                if (t0a > qw0 + 15) continue;
                const int t1 = t0a + 16;
                const bool act1 = (t1 <= qw0 + 15);

                // QK^T (S^T tiles): lane holds q=l16, k=quad*4+r
                f32x4 s0, s1;
                {
                    const int row = (th * 2) * 16 + l16;
                    short8 kf0 = *(const short8*)(Kb0 + row * 32 + (quad * 8 ^ sw8));
                    short8 kf1 = *(const short8*)(Kb1 + row * 32 + (quad * 8 ^ sw8));
                    s0 = MFMA16(kf0, qf[0], fz);
                    s0 = MFMA16(kf1, qf[1], s0);
                }
                if (act1) {
                    const int row = (th * 2 + 1) * 16 + l16;
                    short8 kf0 = *(const short8*)(Kb0 + row * 32 + (quad * 8 ^ sw8));
                    short8 kf1 = *(const short8*)(Kb1 + row * 32 + (quad * 8 ^ sw8));
                    s1 = MFMA16(kf0, qf[0], fz);
                    s1 = MFMA16(kf1, qf[1], s1);
                }

                // softmax numerator, packed in-register
                unsigned u00, u01, u10, u11;
                {
                    const bool full = (t0a + 15) <= qw0;
                    float p[4];
#pragma unroll
                    for (int r = 0; r < 4; r++) {
                        float e = __builtin_amdgcn_exp2f(s0[r]);
                        if (!full)
                            e = (t0a + quad * 4 + r <= qw0 + l16) ? e : 0.f;
                        p[r] = e;
                    }
                    u00 = pack2(p[0], p[1]);
                    u01 = pack2(p[2], p[3]);
                }
                if (act1) {
                    const bool full = (t1 + 15) <= qw0;
                    float p[4];
#pragma unroll
                    for (int r = 0; r < 4; r++) {
                        float e = __builtin_amdgcn_exp2f(s1[r]);
                        if (!full)
                            e = (t1 + quad * 4 + r <= qw0 + l16) ? e : 0.f;
                        p[r] = e;
                    }
                    u10 = pack2(p[0], p[1]);
                    u11 = pack2(p[2], p[3]);
                } else {
                    u10 = 0; u11 = 0;
                }

                // B-fragment: element e of lane-group Q covers t = sigma(8Q+e);
                // Vt stores matching sigma order, so no redistribution needed.
                unsigned pb[4] = {u00, u01, u10, u11};
                short8 pf; __builtin_memcpy(&pf, pb, 16);

                __builtin_amdgcn_s_setprio(1);
                o_l = MFMA16(onesf, pf, o_l);
#pragma unroll
                for (int dt = 0; dt < 4; dt++) {
                    short8 vf = *(const short8*)(Vb0 + th * 2048 + (dt * 16 + l16) * 32 + (quad * 8 ^ sw8));
                    o[dt] = MFMA16(vf, pf, o[dt]);
                }
                __builtin_amdgcn_s_setprio(0);
            }
            slot = nslot;
        }
        // pass-end: all waves done reading ring before next pass restages slot 0
        asm volatile("" ::: "memory");
        __builtin_amdgcn_s_barrier();

        const float rl = 1.f / o_l[0];
        const int q = qw0 + l16;
#pragma unroll
        for (int dt = 0; dt < 4; dt++) {
            ushort4 wv;
            wv.x = f2b(o[dt][0] * rl);
            wv.y = f2b(o[dt][1] * rl);
            wv.z = f2b(o[dt][2] * rl);
            wv.w = f2b(o[dt][3] * rl);
            *(ushort4*)(attn + (size_t)(b * T + q) * 1024 + h * 64 + dt * 16 + quad * 4) = wv;
        }
    }
#undef STAGE
}

// ---------------------------------------------------------------- launch
extern "C" void kernel_launch(void* const* d_in, const int* in_sizes, int n_in,
                              void* d_out, int out_size, void* d_ws, size_t ws_size,
                              hipStream_t stream) {
    const float* x     = (const float*)d_in[0]; // (4,2048,1024)
    const float* w_qkv = (const float*)d_in[1]; // (1024,3072)
    const float* w_out = (const float*)d_in[2]; // (1024,1024)
    float* out = (float*)d_out;

    const size_t MB = 1048576;

    char* ws = (char*)d_ws;
    unsigned short* xb    = (unsigned short*)ws;              // 16 MB
    unsigned short* wqkvT = (unsigned short*)(ws + 16 * MB);  // 6 MB
    unsigned short* woutT = (unsigned short*)(ws + 22 * MB);  // 2 MB
    unsigned short* Qb    = (unsigned short*)(ws + 24 * MB);  // 16 MB (reused as attn out)
    unsigned short* Kb    = (unsigned short*)(ws + 40 * MB);  // 16 MB
    unsigned short* Vt    = (unsigned short*)(ws + 56 * MB);  // 16 MB -> 72 MB total

    // fused preprocessing: 8192 cast blocks + 768 + 256 transpose blocks
    prep_kernel<<<dim3(9216), 256, 0, stream>>>(x, xb, w_qkv, wqkvT, w_out, woutT);

    // fused QKV: [0,256) Q/K (256^2 tiles), [256,512) V (128x256 tiles)
    gemm_qkv<<<dim3(512), 512, 0, stream>>>(xb, wqkvT, wqkvT + (size_t)2048 * 1024,
                                            Qb, Kb, Vt);

    // 512 uniform paired blocks (8 pairs x 64 bh), 512 threads, 48KB ring LDS
    attention_kernel<<<dim3(512), 512, 0, stream>>>(Qb, Kb, Vt, Qb);

    // 128x256 tiles: 64*4 = 256 blocks, 512 threads
    gemm_out<<<dim3(256), 512, 0, stream>>>(Qb, woutT, out);
}

// Round 9
// 236.437 us; speedup vs baseline: 1.0317x; 1.0317x over previous
//
#include <hip/hip_runtime.h>
#include <hip/hip_bf16.h>

typedef short short8 __attribute__((ext_vector_type(8)));
typedef float f32x4 __attribute__((ext_vector_type(4)));
typedef float f32x16 __attribute__((ext_vector_type(16)));

#define MFMA16(a, b, c) __builtin_amdgcn_mfma_f32_16x16x32_bf16((a), (b), (c), 0, 0, 0)
#define MFMA32(a, b, c) __builtin_amdgcn_mfma_f32_32x32x16_bf16((a), (b), (c), 0, 0, 0)

// async global->LDS, 16B per lane; LDS dest = wave-uniform base + lane*16
#define GLOAD16(gp, lp)                                                    \
    __builtin_amdgcn_global_load_lds(                                      \
        (const __attribute__((address_space(1))) unsigned int*)(gp),       \
        (__attribute__((address_space(3))) unsigned int*)(lp), 16, 0, 0)

__device__ __forceinline__ unsigned short f2b(float x) {
    unsigned int u = __float_as_uint(x);
    unsigned int r = u + 0x7FFFu + ((u >> 16) & 1u);
    return (unsigned short)(r >> 16);
}

#if __has_builtin(__builtin_amdgcn_cvt_pk_bf16_f32)
__device__ __forceinline__ unsigned pack2(float a, float b) {
    auto v = __builtin_amdgcn_cvt_pk_bf16_f32(a, b);
    unsigned u;
    __builtin_memcpy(&u, &v, 4);
    return u;
}
#else
__device__ __forceinline__ unsigned pack2(float a, float b) {
    return (unsigned)f2b(a) | ((unsigned)f2b(b) << 16);
}
#endif

// ---------------------------------------------------------------- fused preprocessing
// blocks [0,8192): x -> bf16 cast. [8192,8960): w_qkv transpose. [8960,9216): w_out.
__device__ __forceinline__ void transpose_body(const float* __restrict__ in,
                                               unsigned short* __restrict__ out,
                                               int K, int N, int k0, int n0,
                                               unsigned short* Ls, int tid) {
    const int krow = tid >> 4, nc4 = (tid & 15) * 4;
#pragma unroll
    for (int p = 0; p < 4; p++) {
        float4 v = *(const float4*)(in + (size_t)(k0 + krow + p * 16) * N + n0 + nc4);
        unsigned* d32 = (unsigned*)(Ls + (krow + p * 16) * 66 + nc4);
        d32[0] = pack2(v.x, v.y);
        d32[1] = pack2(v.z, v.w);
    }
    __syncthreads();
    const int n = tid >> 3, kc = (tid & 7) * 8;
#pragma unroll
    for (int p = 0; p < 2; p++) {
        int nn = n + p * 32;
        unsigned short w[8];
#pragma unroll
        for (int j = 0; j < 8; j++) w[j] = Ls[(kc + j) * 66 + nn];
        *(short8*)(out + (size_t)(n0 + nn) * K + k0 + kc) = *(short8*)w;
    }
}

__global__ __launch_bounds__(256) void prep_kernel(const float* __restrict__ x,
                                                   unsigned short* __restrict__ xb,
                                                   const float* __restrict__ w_qkv,
                                                   unsigned short* __restrict__ wqkvT,
                                                   const float* __restrict__ w_out,
                                                   unsigned short* __restrict__ woutT) {
    __shared__ unsigned short Ls[64 * 66];
    const int bid = blockIdx.x, tid = threadIdx.x;
    if (bid < 8192) {
        int i = bid * 256 + tid;   // n4 = 8192*256 exactly
        float4 v = ((const float4*)x)[i];
        ushort4 o;
        o.x = f2b(v.x); o.y = f2b(v.y); o.z = f2b(v.z); o.w = f2b(v.w);
        ((ushort4*)xb)[i] = o;
    } else if (bid < 8960) {
        const int b2 = bid - 8192;          // 768 blocks: N=3072 (48) x K=1024 (16)
        transpose_body(w_qkv, wqkvT, 1024, 3072, (b2 / 48) * 64, (b2 % 48) * 64, Ls, tid);
    } else {
        const int b3 = bid - 8960;          // 256 blocks: 16 x 16
        transpose_body(w_out, woutT, 1024, 1024, (b3 >> 4) * 64, (b3 & 15) * 64, Ls, tid);
    }
}

// ---------------------------------------------------------------- fused QKV GEMM
// blocks [0,256): Q/K path — 256x256 tile, BK=64, 128KB LDS, 4-phase vmcnt(6),
//   swapped MFMA (D^T) -> packed 8B stores. 1 block/CU, exactly 1 round.
// blocks [256,512): V path — 128x256 tile, 96KB LDS, 4-phase vmcnt(5),
//   sigma-permuted LDS-bounce transpose to Vt[bh][64 d][2048 t].
__global__ __launch_bounds__(512, 2) void gemm_qkv(const unsigned short* __restrict__ A,
                                                   const unsigned short* __restrict__ BtQK,
                                                   const unsigned short* __restrict__ BtV,
                                                   unsigned short* __restrict__ Qb,
                                                   unsigned short* __restrict__ Kb,
                                                   unsigned short* __restrict__ Vt) {
    __shared__ __align__(16) unsigned short smem[65536]; // 128KB, V path uses first 96KB

    const int tid  = threadIdx.x;
    const int wave = tid >> 6;
    const int lane = tid & 63;
    const int l32  = lane & 31;
    const int hi   = lane >> 5;
    const int wr   = wave >> 2;
    const int wc   = wave & 3;
    const int sw7  = l32 & 7;
    const int srow = tid >> 3;
    const int cswz = (((tid & 7) ^ ((tid >> 3) & 7)) * 8);

    if (blockIdx.x < 256) {
        // ---------------- Q/K path ----------------
        const int bid = blockIdx.x;
        const int sid = (bid & 7) * 32 + (bid >> 3);
        const int bx  = sid & 7;
        const int by  = sid >> 3;
        const int m0 = by * 256;
        const int n0 = bx * 256;

        const unsigned short* gA = A    + (size_t)(m0 + srow) * 1024 + cswz;
        const unsigned short* gB = BtQK + (size_t)(n0 + srow) * 1024 + cswz;

#define STAGE_A(buf, h, kt) do {                                              \
        const unsigned short* _g = gA + (size_t)((h) * 128) * 1024 + (kt) * 64; \
        unsigned short* _l = smem + (buf) * 16384 + (h) * 8192 + wave * 512;  \
        GLOAD16(_g, _l);                                                      \
        GLOAD16(_g + 65536, _l + 4096);                                       \
    } while (0)
#define STAGE_B(buf, h, kt) do {                                              \
        const unsigned short* _g = gB + (size_t)((h) * 128) * 1024 + (kt) * 64; \
        unsigned short* _l = smem + 32768 + (buf) * 16384 + (h) * 8192 + wave * 512; \
        GLOAD16(_g, _l);                                                      \
        GLOAD16(_g + 65536, _l + 4096);                                       \
    } while (0)

        const int aoff = (wr * 128 + l32) * 64;
        const int boff = (wc * 64 + l32) * 64;

        f32x16 acc[4][2] = {};

        STAGE_A(0, 0, 0); STAGE_A(0, 1, 0); STAGE_B(0, 0, 0); STAGE_B(0, 1, 0);
        STAGE_B(1, 0, 1); STAGE_B(1, 1, 1); STAGE_A(1, 0, 1);
        asm volatile("s_waitcnt vmcnt(6)" ::: "memory");
        __builtin_amdgcn_s_barrier();

#pragma unroll
        for (int t = 0; t < 16; ++t) {
            const int b = t & 1;
            const unsigned short* Ab = smem + b * 16384;
            const unsigned short* Bb = smem + 32768 + b * 16384;

            short8 afLo[2][4], afHi[2][4], bf0[4], bf1[4];

            // phase 1: afLo + bf0 | stage A1(t+1) | q0
#pragma unroll
            for (int rf = 0; rf < 2; ++rf)
#pragma unroll
                for (int ks = 0; ks < 4; ++ks)
                    afLo[rf][ks] = *(const short8*)(Ab + aoff + rf * 2048 + (((ks * 2 + hi) ^ sw7) * 8));
#pragma unroll
            for (int ks = 0; ks < 4; ++ks)
                bf0[ks] = *(const short8*)(Bb + boff + (((ks * 2 + hi) ^ sw7) * 8));
            if (t + 1 < 16) STAGE_A(b ^ 1, 1, t + 1);
            __builtin_amdgcn_s_barrier();
            asm volatile("s_waitcnt lgkmcnt(0)" ::: "memory");
            __builtin_amdgcn_s_setprio(1);
#pragma unroll
            for (int ks = 0; ks < 4; ++ks) {
                acc[0][0] = MFMA32(bf0[ks], afLo[0][ks], acc[0][0]);
                acc[1][0] = MFMA32(bf0[ks], afLo[1][ks], acc[1][0]);
            }
            __builtin_amdgcn_s_setprio(0);
            __builtin_amdgcn_s_barrier();

            // phase 2: bf1 | q1
#pragma unroll
            for (int ks = 0; ks < 4; ++ks)
                bf1[ks] = *(const short8*)(Bb + boff + 2048 + (((ks * 2 + hi) ^ sw7) * 8));
            __builtin_amdgcn_s_barrier();
            asm volatile("s_waitcnt lgkmcnt(0)" ::: "memory");
            __builtin_amdgcn_s_setprio(1);
#pragma unroll
            for (int ks = 0; ks < 4; ++ks) {
                acc[0][1] = MFMA32(bf1[ks], afLo[0][ks], acc[0][1]);
                acc[1][1] = MFMA32(bf1[ks], afLo[1][ks], acc[1][1]);
            }
            __builtin_amdgcn_s_setprio(0);
            __builtin_amdgcn_s_barrier();

            // phase 3: afHi | stage B0,B1(t+2) | q2
#pragma unroll
            for (int rf = 0; rf < 2; ++rf)
#pragma unroll
                for (int ks = 0; ks < 4; ++ks)
                    afHi[rf][ks] = *(const short8*)(Ab + aoff + (2 + rf) * 2048 + (((ks * 2 + hi) ^ sw7) * 8));
            if (t + 2 < 16) { STAGE_B(b, 0, t + 2); STAGE_B(b, 1, t + 2); }
            __builtin_amdgcn_s_barrier();
            asm volatile("s_waitcnt lgkmcnt(0)" ::: "memory");
            __builtin_amdgcn_s_setprio(1);
#pragma unroll
            for (int ks = 0; ks < 4; ++ks) {
                acc[2][0] = MFMA32(bf0[ks], afHi[0][ks], acc[2][0]);
                acc[3][0] = MFMA32(bf0[ks], afHi[1][ks], acc[3][0]);
            }
            __builtin_amdgcn_s_setprio(0);
            __builtin_amdgcn_s_barrier();

            // phase 4: stage A0(t+2) | counted vmcnt | q3
            if (t + 2 < 16) {
                STAGE_A(b, 0, t + 2);
                asm volatile("s_waitcnt vmcnt(6)" ::: "memory");
            } else {
                asm volatile("s_waitcnt vmcnt(0)" ::: "memory");
            }
            __builtin_amdgcn_s_barrier();
            __builtin_amdgcn_s_setprio(1);
#pragma unroll
            for (int ks = 0; ks < 4; ++ks) {
                acc[2][1] = MFMA32(bf1[ks], afHi[0][ks], acc[2][1]);
                acc[3][1] = MFMA32(bf1[ks], afHi[1][ks], acc[3][1]);
            }
            __builtin_amdgcn_s_setprio(0);
            __builtin_amdgcn_s_barrier();
        }
#undef STAGE_A
#undef STAGE_B

        // D^T layout: m-row = frag-row(l32), n-col = (r&3)+8*(r>>2)+4*hi
        unsigned short* outp = (n0 < 1024) ? Qb : Kb;
        const int cb = (n0 < 1024) ? n0 : n0 - 1024;
        const float QS = (n0 < 1024) ? 0.125f * 1.44269504f : 1.0f;
#pragma unroll
        for (int rf = 0; rf < 4; ++rf) {
            const int row = m0 + wr * 128 + rf * 32 + l32;
#pragma unroll
            for (int cf = 0; cf < 2; ++cf)
#pragma unroll
                for (int g = 0; g < 4; ++g) {
                    const int col = cb + wc * 64 + cf * 32 + g * 8 + 4 * hi;
                    uint2 v;
                    v.x = pack2(acc[rf][cf][4 * g + 0] * QS, acc[rf][cf][4 * g + 1] * QS);
                    v.y = pack2(acc[rf][cf][4 * g + 2] * QS, acc[rf][cf][4 * g + 3] * QS);
                    *(uint2*)(outp + (size_t)row * 1024 + col) = v;
                }
        }
    } else {
        // ---------------- V path ----------------
        const int bid = blockIdx.x - 256;
        const int sid = (bid & 7) * 32 + (bid >> 3);
        const int bx  = sid & 3;
        const int by  = sid >> 2;
        const int m0 = by * 128;
        const int n0 = bx * 256;

        const unsigned short* gA = A   + (size_t)(m0 + srow) * 1024 + cswz;
        const unsigned short* gB = BtV + (size_t)(n0 + srow) * 1024 + cswz;

#define STAGE_A(buf, h, kt) do {                                              \
        const unsigned short* _g = gA + (size_t)((h) * 64) * 1024 + (kt) * 64; \
        unsigned short* _l = smem + (buf) * 8192 + (h) * 4096 + wave * 512;   \
        GLOAD16(_g, _l);                                                      \
    } while (0)
#define STAGE_B(buf, h, kt) do {                                              \
        const unsigned short* _g = gB + (size_t)((h) * 128) * 1024 + (kt) * 64; \
        unsigned short* _l = smem + 16384 + (buf) * 16384 + (h) * 8192 + wave * 512; \
        GLOAD16(_g, _l);                                                      \
        GLOAD16(_g + 65536, _l + 4096);                                       \
    } while (0)

        const int aoff = (wr * 64 + l32) * 64;
        const int boff = (wc * 64 + l32) * 64;

        f32x16 acc[2][2] = {};

        STAGE_A(0, 0, 0); STAGE_A(0, 1, 0); STAGE_B(0, 0, 0); STAGE_B(0, 1, 0);
        STAGE_B(1, 0, 1); STAGE_B(1, 1, 1); STAGE_A(1, 0, 1);
        asm volatile("s_waitcnt vmcnt(5)" ::: "memory");
        __builtin_amdgcn_s_barrier();

#pragma unroll
        for (int t = 0; t < 16; ++t) {
            const int b = t & 1;
            const unsigned short* Ab = smem + b * 8192;
            const unsigned short* Bb = smem + 16384 + b * 16384;

            short8 af0[4], af1[4], bf0[4], bf1[4];

            // phase 1: af0 + bf0 | stage A1(t+1) | q0
#pragma unroll
            for (int ks = 0; ks < 4; ++ks)
                af0[ks] = *(const short8*)(Ab + aoff + (((ks * 2 + hi) ^ sw7) * 8));
#pragma unroll
            for (int ks = 0; ks < 4; ++ks)
                bf0[ks] = *(const short8*)(Bb + boff + (((ks * 2 + hi) ^ sw7) * 8));
            if (t + 1 < 16) STAGE_A(b ^ 1, 1, t + 1);
            __builtin_amdgcn_s_barrier();
            asm volatile("s_waitcnt lgkmcnt(0)" ::: "memory");
            __builtin_amdgcn_s_setprio(1);
#pragma unroll
            for (int ks = 0; ks < 4; ++ks)
                acc[0][0] = MFMA32(af0[ks], bf0[ks], acc[0][0]);
            __builtin_amdgcn_s_setprio(0);
            __builtin_amdgcn_s_barrier();

            // phase 2: bf1 | q1
#pragma unroll
            for (int ks = 0; ks < 4; ++ks)
                bf1[ks] = *(const short8*)(Bb + boff + 2048 + (((ks * 2 + hi) ^ sw7) * 8));
            __builtin_amdgcn_s_barrier();
            asm volatile("s_waitcnt lgkmcnt(0)" ::: "memory");
            __builtin_amdgcn_s_setprio(1);
#pragma unroll
            for (int ks = 0; ks < 4; ++ks)
                acc[0][1] = MFMA32(af0[ks], bf1[ks], acc[0][1]);
            __builtin_amdgcn_s_setprio(0);
            __builtin_amdgcn_s_barrier();

            // phase 3: af1 | stage B0,B1(t+2) | q2
#pragma unroll
            for (int ks = 0; ks < 4; ++ks)
                af1[ks] = *(const short8*)(Ab + aoff + 2048 + (((ks * 2 + hi) ^ sw7) * 8));
            if (t + 2 < 16) { STAGE_B(b, 0, t + 2); STAGE_B(b, 1, t + 2); }
            __builtin_amdgcn_s_barrier();
            asm volatile("s_waitcnt lgkmcnt(0)" ::: "memory");
            __builtin_amdgcn_s_setprio(1);
#pragma unroll
            for (int ks = 0; ks < 4; ++ks)
                acc[1][0] = MFMA32(af1[ks], bf0[ks], acc[1][0]);
            __builtin_amdgcn_s_setprio(0);
            __builtin_amdgcn_s_barrier();

            // phase 4: stage A0(t+2) | counted vmcnt | q3
            if (t + 2 < 16) {
                STAGE_A(b, 0, t + 2);
                asm volatile("s_waitcnt vmcnt(5)" ::: "memory");
            } else {
                asm volatile("s_waitcnt vmcnt(0)" ::: "memory");
            }
            __builtin_amdgcn_s_barrier();
            __builtin_amdgcn_s_setprio(1);
#pragma unroll
            for (int ks = 0; ks < 4; ++ks)
                acc[1][1] = MFMA32(af1[ks], bf1[ks], acc[1][1]);
            __builtin_amdgcn_s_setprio(0);
            __builtin_amdgcn_s_barrier();
        }
#undef STAGE_A
#undef STAGE_B

        // bounce: [t][d] -> Vt[bh][d][t] with sigma order (sigma(8Q+e)=4Q+(e&3)+16*(e>=4))
        const int bb = m0 >> 11, t0b = m0 & 2047;
        const int hbase = n0 >> 6;
        unsigned short* reg = smem + wc * 8192;
#pragma unroll
        for (int rf = 0; rf < 2; ++rf)
#pragma unroll
            for (int cf = 0; cf < 2; ++cf)
#pragma unroll
                for (int rg = 0; rg < 4; ++rg) {
                    const int tl = wr * 64 + rf * 32 + rg * 8 + 4 * hi;
                    const int d  = cf * 32 + l32;
                    const int w  = d * 64 + ((tl >> 1) ^ (4 * (d & 7)));
                    uint2 v;
                    v.x = pack2(acc[rf][cf][4 * rg + 0], acc[rf][cf][4 * rg + 1]);
                    v.y = pack2(acc[rf][cf][4 * rg + 2], acc[rf][cf][4 * rg + 3]);
                    *(uint2*)(reg + 2 * w) = v;
                }
        __syncthreads();
#pragma unroll
        for (int it = 0; it < 8; ++it) {
            const int id = it * 512 + tid;
            const int hh = id >> 10, d = (id >> 4) & 63, k = id & 15;
            const int kb = k >> 2, kl = k & 3;
            const int xx = 4 * (d & 7);
            const unsigned short* bp = smem + hh * 8192 + 2 * (d * 64);
            uint2 lo  = *(const uint2*)(bp + 2 * ((16 * kb + 2 * kl) ^ xx));
            uint2 hi2 = *(const uint2*)(bp + 2 * ((16 * kb + 2 * kl + 8) ^ xx));
            uint2 parts[2] = {lo, hi2};
            short8 v; __builtin_memcpy(&v, parts, 16);
            *(short8*)(Vt + ((size_t)((bb * 16 + hbase + hh) * 64 + d)) * 2048 + t0b + k * 8) = v;
        }
    }
}

// ---------------------------------------------------------------- out-proj GEMM
// 128x256 tile, BK=64, 8 waves (2Mx4N), double-buffered 96KB LDS, 4-phase
// counted-vmcnt(5) schedule (per-wave 64x64, acc[2][2]).
__global__ __launch_bounds__(512, 2) void gemm_out(const unsigned short* __restrict__ A,
                                                   const unsigned short* __restrict__ Bt,
                                                   float* __restrict__ C) {
    __shared__ __align__(16) unsigned short smem[49152]; // A[2][8192] | B[2][16384]

    const int tid  = threadIdx.x;
    const int wave = tid >> 6;
    const int lane = tid & 63;
    const int l32  = lane & 31;
    const int hi   = lane >> 5;
    const int wr   = wave >> 2;   // 0..1 (M)
    const int wc   = wave & 3;    // 0..3 (N)

    const int bid = blockIdx.x;
    const int sid = (bid & 7) * 32 + (bid >> 3);
    const int bx  = sid & 3;      // 4 N-blocks
    const int by  = sid >> 2;     // 64 M-blocks
    const int m0 = by * 128;
    const int n0 = bx * 256;

    const int srow = tid >> 3;
    const int cswz = (((tid & 7) ^ ((tid >> 3) & 7)) * 8);
    const unsigned short* gA = A  + (size_t)(m0 + srow) * 1024 + cswz;
    const unsigned short* gB = Bt + (size_t)(n0 + srow) * 1024 + cswz;

#define STAGE_A(buf, h, kt) do {                                              \
        const unsigned short* _g = gA + (size_t)((h) * 64) * 1024 + (kt) * 64; \
        unsigned short* _l = smem + (buf) * 8192 + (h) * 4096 + wave * 512;   \
        GLOAD16(_g, _l);                                                      \
    } while (0)
#define STAGE_B(buf, h, kt) do {                                              \
        const unsigned short* _g = gB + (size_t)((h) * 128) * 1024 + (kt) * 64; \
        unsigned short* _l = smem + 16384 + (buf) * 16384 + (h) * 8192 + wave * 512; \
        GLOAD16(_g, _l);                                                      \
        GLOAD16(_g + 65536, _l + 4096);                                       \
    } while (0)

    const int sw7  = l32 & 7;
    const int aoff = (wr * 64 + l32) * 64;
    const int boff = (wc * 64 + l32) * 64;

    f32x16 acc[2][2] = {};

    STAGE_A(0, 0, 0); STAGE_A(0, 1, 0); STAGE_B(0, 0, 0); STAGE_B(0, 1, 0);
    STAGE_B(1, 0, 1); STAGE_B(1, 1, 1); STAGE_A(1, 0, 1);
    asm volatile("s_waitcnt vmcnt(5)" ::: "memory");
    __builtin_amdgcn_s_barrier();

#pragma unroll
    for (int t = 0; t < 16; ++t) {
        const int b = t & 1;
        const unsigned short* Ab = smem + b * 8192;
        const unsigned short* Bb = smem + 16384 + b * 16384;

        short8 af0[4], af1[4], bf0[4], bf1[4];

        // phase 1: af0 + bf0 | stage A1(t+1) | q0
#pragma unroll
        for (int ks = 0; ks < 4; ++ks)
            af0[ks] = *(const short8*)(Ab + aoff + (((ks * 2 + hi) ^ sw7) * 8));
#pragma unroll
        for (int ks = 0; ks < 4; ++ks)
            bf0[ks] = *(const short8*)(Bb + boff + (((ks * 2 + hi) ^ sw7) * 8));
        if (t + 1 < 16) STAGE_A(b ^ 1, 1, t + 1);
        __builtin_amdgcn_s_barrier();
        asm volatile("s_waitcnt lgkmcnt(0)" ::: "memory");
        __builtin_amdgcn_s_setprio(1);
#pragma unroll
        for (int ks = 0; ks < 4; ++ks)
            acc[0][0] = MFMA32(af0[ks], bf0[ks], acc[0][0]);
        __builtin_amdgcn_s_setprio(0);
        __builtin_amdgcn_s_barrier();

        // phase 2: bf1 | q1
#pragma unroll
        for (int ks = 0; ks < 4; ++ks)
            bf1[ks] = *(const short8*)(Bb + boff + 2048 + (((ks * 2 + hi) ^ sw7) * 8));
        __builtin_amdgcn_s_barrier();
        asm volatile("s_waitcnt lgkmcnt(0)" ::: "memory");
        __builtin_amdgcn_s_setprio(1);
#pragma unroll
        for (int ks = 0; ks < 4; ++ks)
            acc[0][1] = MFMA32(af0[ks], bf1[ks], acc[0][1]);
        __builtin_amdgcn_s_setprio(0);
        __builtin_amdgcn_s_barrier();

        // phase 3: af1 | stage B0,B1(t+2) | q2
#pragma unroll
        for (int ks = 0; ks < 4; ++ks)
            af1[ks] = *(const short8*)(Ab + aoff + 2048 + (((ks * 2 + hi) ^ sw7) * 8));
        if (t + 2 < 16) { STAGE_B(b, 0, t + 2); STAGE_B(b, 1, t + 2); }
        __builtin_amdgcn_s_barrier();
        asm volatile("s_waitcnt lgkmcnt(0)" ::: "memory");
        __builtin_amdgcn_s_setprio(1);
#pragma unroll
        for (int ks = 0; ks < 4; ++ks)
            acc[1][0] = MFMA32(af1[ks], bf0[ks], acc[1][0]);
        __builtin_amdgcn_s_setprio(0);
        __builtin_amdgcn_s_barrier();

        // phase 4: stage A0(t+2) | counted vmcnt | q3
        if (t + 2 < 16) {
            STAGE_A(b, 0, t + 2);
            asm volatile("s_waitcnt vmcnt(5)" ::: "memory");
        } else {
            asm volatile("s_waitcnt vmcnt(0)" ::: "memory");
        }
        __builtin_amdgcn_s_barrier();
        __builtin_amdgcn_s_setprio(1);
#pragma unroll
        for (int ks = 0; ks < 4; ++ks)
            acc[1][1] = MFMA32(af1[ks], bf1[ks], acc[1][1]);
        __builtin_amdgcn_s_setprio(0);
        __builtin_amdgcn_s_barrier();
    }
#undef STAGE_A
#undef STAGE_B

#pragma unroll
    for (int rf = 0; rf < 2; ++rf)
#pragma unroll
        for (int cf = 0; cf < 2; ++cf)
#pragma unroll
            for (int r = 0; r < 16; ++r) {
                int row = m0 + wr * 64 + rf * 32 + (r & 3) + 8 * (r >> 2) + 4 * hi;
                int col = n0 + wc * 64 + cf * 32 + l32;
                C[(size_t)row * 1024 + col] = acc[rf][cf][r];
            }
}

// ---------------------------------------------------------------- flash attention (S^T formulation)
// 1024 blocks x 512 threads, ONE 128-q block each; qb from a work-balanced
// permutation (nibble-packed 0x765489AB3210CDEF) so blocks {c, c+256, c+512,
// c+768} sum to exactly 34 work-units per CU under round-robin dispatch.
// 2-slot 32KB LDS double buffer (-> 4 blocks/CU = 32 waves/CU, the HW cap),
// 2 barriers/tile, counted vmcnt(2) prefetch distance 1.
// In-register sigma-P, MFMA-ones row-sum. Q pre-scaled.
__global__ __launch_bounds__(512, 4) void attention_kernel(const unsigned short* Qb,
                                                           const unsigned short* Kb,
                                                           const unsigned short* Vt,
                                                           unsigned short* attn) {
    const int T = 2048;
    const int bi = blockIdx.x;
    const unsigned long long PERM = 0x765489AB3210CDEFull;
    const int qb = (int)((PERM >> (4 * (bi >> 6))) & 15ull);
    const int hb = bi & 63;
    const int b = hb >> 4, h = hb & 15;
    const int tid = threadIdx.x, wave = tid >> 6, lane = tid & 63;
    const int l16 = lane & 15, quad = lane >> 4;
    const int qw0 = qb * 128 + wave * 16;

    const unsigned short* Qp  = Qb + (size_t)b * T * 1024 + h * 64;
    const unsigned short* Kp  = Kb + (size_t)b * T * 1024 + h * 64;
    const unsigned short* Vbh = Vt + ((size_t)(b * 16 + h) * 64) * 2048;

    // slot (8192 shorts): K[2][64t][32d] (4096) | V[2][64d][32t] (4096)
    __shared__ __align__(16) unsigned short smem[2][8192];

    const f32x4 fz = {};
    short8 onesf;
#pragma unroll
    for (int e = 0; e < 8; e++) onesf[e] = (short)0x3F80;

    const int srow = lane >> 2;
    const int scol = (((lane & 3) ^ ((lane >> 3) & 3)) * 8);
    const int sw8  = ((l16 >> 1) & 3) * 8;

    // staging assignment: waves 0-3 -> K (panel=d-half, chunk-pair), 4-7 -> V
    const unsigned short* gs;
    size_t ktstep, jstep;
    int lofs;
    if (wave < 4) {
        const int p = wave >> 1, cp = wave & 1;
        gs = Kp + (size_t)(cp * 32 + srow) * 1024 + p * 32 + scol;
        ktstep = (size_t)64 * 1024; jstep = (size_t)16 * 1024;
        lofs = p * 2048 + cp * 1024;
    } else {
        const int u = wave - 4, th = u >> 1, cp = u & 1;
        gs = Vbh + (size_t)(cp * 32 + srow) * 2048 + th * 32 + scol;
        ktstep = (size_t)64; jstep = (size_t)16 * 2048;
        lofs = 4096 + th * 2048 + cp * 1024;
    }

#define STAGE(slot, k64) do {                                  \
        const unsigned short* _g = gs + (size_t)(k64) * ktstep; \
        unsigned short* _l = &smem[slot][0] + lofs;             \
        GLOAD16(_g, _l);                                        \
        GLOAD16(_g + jstep, _l + 512);                          \
    } while (0)

    short8 qf[2];
#pragma unroll
    for (int kd = 0; kd < 2; kd++)
        qf[kd] = *(const short8*)(Qp + (size_t)(qw0 + l16) * 1024 + kd * 32 + quad * 8);
    asm volatile("" ::: "memory");

    f32x4 o[4] = {};
    f32x4 o_l = {};

    const int nt = 2 * qb + 2;              // 64-t tiles 0..nt-1
    STAGE(0, 0);
    for (int j = 0; j < nt; ++j) {
        const int slot = j & 1;
        // stage slot^1 for j+1: slot^1 was last computed in iter j-1, whose
        // trailing barrier has already passed -> safe to overwrite.
        if (j + 1 < nt) {
            STAGE(slot ^ 1, j + 1);
            asm volatile("s_waitcnt vmcnt(2)" ::: "memory");
        } else {
            asm volatile("s_waitcnt vmcnt(0)" ::: "memory");
        }
        __builtin_amdgcn_s_barrier();
        asm volatile("" ::: "memory");

        const int tk0 = j * 64;
        const unsigned short* Kb0 = &smem[slot][0];
        const unsigned short* Kb1 = Kb0 + 2048;
        const unsigned short* Vb0 = Kb0 + 4096;

#pragma unroll
        for (int th = 0; th < 2; th++) {
            const int t0a = tk0 + th * 32;
            if (t0a > qw0 + 15) continue;
            const int t1 = t0a + 16;
            const bool act1 = (t1 <= qw0 + 15);

            // QK^T (S^T tiles): lane holds q=l16, k=quad*4+r
            f32x4 s0, s1;
            {
                const int row = (th * 2) * 16 + l16;
                short8 kf0 = *(const short8*)(Kb0 + row * 32 + (quad * 8 ^ sw8));
                short8 kf1 = *(const short8*)(Kb1 + row * 32 + (quad * 8 ^ sw8));
                s0 = MFMA16(kf0, qf[0], fz);
                s0 = MFMA16(kf1, qf[1], s0);
            }
            if (act1) {
                const int row = (th * 2 + 1) * 16 + l16;
                short8 kf0 = *(const short8*)(Kb0 + row * 32 + (quad * 8 ^ sw8));
                short8 kf1 = *(const short8*)(Kb1 + row * 32 + (quad * 8 ^ sw8));
                s1 = MFMA16(kf0, qf[0], fz);
                s1 = MFMA16(kf1, qf[1], s1);
            }

            // softmax numerator, packed in-register
            unsigned u00, u01, u10, u11;
            {
                const bool full = (t0a + 15) <= qw0;
                float p[4];
#pragma unroll
                for (int r = 0; r < 4; r++) {
                    float e = __builtin_amdgcn_exp2f(s0[r]);
                    if (!full)
                        e = (t0a + quad * 4 + r <= qw0 + l16) ? e : 0.f;
                    p[r] = e;
                }
                u00 = pack2(p[0], p[1]);
                u01 = pack2(p[2], p[3]);
            }
            if (act1) {
                const bool full = (t1 + 15) <= qw0;
                float p[4];
#pragma unroll
                for (int r = 0; r < 4; r++) {
                    float e = __builtin_amdgcn_exp2f(s1[r]);
                    if (!full)
                        e = (t1 + quad * 4 + r <= qw0 + l16) ? e : 0.f;
                    p[r] = e;
                }
                u10 = pack2(p[0], p[1]);
                u11 = pack2(p[2], p[3]);
            } else {
                u10 = 0; u11 = 0;
            }

            // B-fragment: element e of lane-group Q covers t = sigma(8Q+e);
            // Vt stores matching sigma order, so no redistribution needed.
            unsigned pb[4] = {u00, u01, u10, u11};
            short8 pf; __builtin_memcpy(&pf, pb, 16);

            __builtin_amdgcn_s_setprio(1);
            o_l = MFMA16(onesf, pf, o_l);
#pragma unroll
            for (int dt = 0; dt < 4; dt++) {
                short8 vf = *(const short8*)(Vb0 + th * 2048 + (dt * 16 + l16) * 32 + (quad * 8 ^ sw8));
                o[dt] = MFMA16(vf, pf, o[dt]);
            }
            __builtin_amdgcn_s_setprio(0);
        }
        asm volatile("" ::: "memory");
        __builtin_amdgcn_s_barrier();
    }
#undef STAGE

    const float rl = 1.f / o_l[0];
    const int q = qw0 + l16;
#pragma unroll
    for (int dt = 0; dt < 4; dt++) {
        ushort4 wv;
        wv.x = f2b(o[dt][0] * rl);
        wv.y = f2b(o[dt][1] * rl);
        wv.z = f2b(o[dt][2] * rl);
        wv.w = f2b(o[dt][3] * rl);
        *(ushort4*)(attn + (size_t)(b * T + q) * 1024 + h * 64 + dt * 16 + quad * 4) = wv;
    }
}

// ---------------------------------------------------------------- launch
extern "C" void kernel_launch(void* const* d_in, const int* in_sizes, int n_in,
                              void* d_out, int out_size, void* d_ws, size_t ws_size,
                              hipStream_t stream) {
    const float* x     = (const float*)d_in[0]; // (4,2048,1024)
    const float* w_qkv = (const float*)d_in[1]; // (1024,3072)
    const float* w_out = (const float*)d_in[2]; // (1024,1024)
    float* out = (float*)d_out;

    const size_t MB = 1048576;

    char* ws = (char*)d_ws;
    unsigned short* xb    = (unsigned short*)ws;              // 16 MB
    unsigned short* wqkvT = (unsigned short*)(ws + 16 * MB);  // 6 MB
    unsigned short* woutT = (unsigned short*)(ws + 22 * MB);  // 2 MB
    unsigned short* Qb    = (unsigned short*)(ws + 24 * MB);  // 16 MB (reused as attn out)
    unsigned short* Kb    = (unsigned short*)(ws + 40 * MB);  // 16 MB
    unsigned short* Vt    = (unsigned short*)(ws + 56 * MB);  // 16 MB -> 72 MB total

    // fused preprocessing: 8192 cast blocks + 768 + 256 transpose blocks
    prep_kernel<<<dim3(9216), 256, 0, stream>>>(x, xb, w_qkv, wqkvT, w_out, woutT);

    // fused QKV: [0,256) Q/K (256^2 tiles), [256,512) V (128x256 tiles)
    gemm_qkv<<<dim3(512), 512, 0, stream>>>(xb, wqkvT, wqkvT + (size_t)2048 * 1024,
                                            Qb, Kb, Vt);

    // 1024 blocks (work-balanced qb permutation x 64 bh), 512 threads, 32KB dbuf
    attention_kernel<<<dim3(1024), 512, 0, stream>>>(Qb, Kb, Vt, Qb);

    // 128x256 tiles: 64*4 = 256 blocks, 512 threads
    gemm_out<<<dim3(256), 512, 0, stream>>>(Qb, woutT, out);
}